// Round 2
// baseline (457.589 us; speedup 1.0000x reference)
//
#include <hip/hip_runtime.h>
#include <cstdint>
#include <cstddef>

// Problem constants
#define B_ 8
#define NT 1024
#define NK 1024
#define D_ 768
#define H_ 8
#define HD_ 96
#define CLS_ 20
#define L_ 1044
#define SCALE_ 0.10206207261596577f
#define LOG2E_ 1.4426950408889634f
#define TQ 16
// integer mask threshold: bits < THR  <=>  uniform(bits) < 0.3f (exact)
#define MASK_THR 1288490496u

typedef __attribute__((ext_vector_type(8))) short bf16x8;
typedef __attribute__((ext_vector_type(4))) float f32x4;

__device__ __forceinline__ unsigned short f2bf(float f) {
    uint32_t u = __float_as_uint(f);
    u += 0x7FFFu + ((u >> 16) & 1u);   // RNE (no NaN inputs here)
    return (unsigned short)(u >> 16);
}

__device__ __forceinline__ float fexp2(float x) {
#if __has_builtin(__builtin_amdgcn_exp2f)
    return __builtin_amdgcn_exp2f(x);
#else
    return __expf(x * 0.6931471805599453f);
#endif
}

// async global->LDS, 16B per lane; LDS dest = wave-uniform base + lane*16
__device__ __forceinline__ void gll16(const void* g, void* l) {
    __builtin_amdgcn_global_load_lds(
        (const __attribute__((address_space(1))) unsigned int*)g,
        (__attribute__((address_space(3))) unsigned int*)l,
        16, 0, 0);
}

// ---------------------------------------------------------------------------
// JAX threefry2x32, partitionable scheme (verified round 3):
// counter = (0, g), output bits = x0 ^ x1. key = (0, 42).
// ---------------------------------------------------------------------------
__device__ __forceinline__ uint32_t tf_bits(uint32_t g) {
    const uint32_t k0 = 0u, k1 = 42u;
    const uint32_t ks2 = k0 ^ k1 ^ 0x1BD11BDAu;
    uint32_t x0 = 0u, x1 = g;

    x0 += k0; x1 += k1;
#define TF_ROUND(r) { x0 += x1; x1 = __builtin_rotateleft32(x1, (r)); x1 ^= x0; }
    TF_ROUND(13) TF_ROUND(15) TF_ROUND(26) TF_ROUND(6)
    x0 += k1;  x1 += ks2 + 1u;
    TF_ROUND(17) TF_ROUND(29) TF_ROUND(16) TF_ROUND(24)
    x0 += ks2; x1 += k0 + 2u;
    TF_ROUND(13) TF_ROUND(15) TF_ROUND(26) TF_ROUND(6)
    x0 += k0;  x1 += k1 + 3u;
    TF_ROUND(17) TF_ROUND(29) TF_ROUND(16) TF_ROUND(24)
    x0 += k1;  x1 += ks2 + 4u;
    TF_ROUND(13) TF_ROUND(15) TF_ROUND(26) TF_ROUND(6)
    x0 += ks2; x1 += k0 + 5u;
#undef TF_ROUND
    return x0 ^ x1;
}

// ---------------------------------------------------------------------------
// fp32 -> bf16 flat convert (float4 granular)
// ---------------------------------------------------------------------------
__global__ __launch_bounds__(256) void conv_bf16(
    const float* __restrict__ src, unsigned short* __restrict__ dst, int n4)
{
    int i = blockIdx.x * 256 + threadIdx.x;
    if (i < n4) {
        float4 v = ((const float4*)src)[i];
        ushort4 o;
        o.x = f2bf(v.x); o.y = f2bf(v.y); o.z = f2bf(v.z); o.w = f2bf(v.w);
        ((ushort4*)dst)[i] = o;
    }
}

// ---------------------------------------------------------------------------
// weight transpose: W[768][Nn] fp32 -> Wt[Nn][768] bf16 (* scale), 32x32 tiles
// ---------------------------------------------------------------------------
__global__ __launch_bounds__(256) void trw_bf16(
    const float* __restrict__ W, unsigned short* __restrict__ Wt, int Nn,
    float scale)
{
    __shared__ unsigned short tile[32][36];
    const int n0 = blockIdx.x * 32, k0 = blockIdx.y * 32;
    const int t = threadIdx.x, r = t >> 3, c4 = (t & 7) * 4;

    float4 v = *(const float4*)&W[(size_t)(k0 + r) * Nn + n0 + c4];
    tile[r][c4 + 0] = f2bf(v.x * scale);
    tile[r][c4 + 1] = f2bf(v.y * scale);
    tile[r][c4 + 2] = f2bf(v.z * scale);
    tile[r][c4 + 3] = f2bf(v.w * scale);
    __syncthreads();

    ushort4 o;
    o.x = tile[c4 + 0][r];
    o.y = tile[c4 + 1][r];
    o.z = tile[c4 + 2][r];
    o.w = tile[c4 + 3][r];
    *(ushort4*)&Wt[(size_t)(n0 + r) * 768 + k0 + c4] = o;
}

// ---------------------------------------------------------------------------
// V transpose: kv16[8192][1536] bf16 (V half at col 768+h*96) ->
//              vT[(b*8+h)*96 + d][1024] bf16
// ---------------------------------------------------------------------------
__global__ __launch_bounds__(256) void trv(
    const unsigned short* __restrict__ kv16, unsigned short* __restrict__ vT)
{
    const int bid = blockIdx.x;       // (b*8+h)*16 + nt
    const int nt = bid & 15, bh = bid >> 4;
    const int b = bh >> 3, h = bh & 7;
    const int n0 = nt * 64;
    const int t = threadIdx.x;

    __shared__ unsigned short tile[64][104];

    for (int i = t; i < 768; i += 256) {
        int r = i / 12, c = i % 12;
        *(uint4*)&tile[r][c * 8] =
            *(const uint4*)&kv16[(size_t)(b * 1024 + n0 + r) * 1536 + 768 + h * 96 + c * 8];
    }
    __syncthreads();

    for (int i = t; i < 768; i += 256) {
        int d = i >> 3, c = i & 7;
        ushort4 lo, hi;
        lo.x = tile[c * 8 + 0][d]; lo.y = tile[c * 8 + 1][d];
        lo.z = tile[c * 8 + 2][d]; lo.w = tile[c * 8 + 3][d];
        hi.x = tile[c * 8 + 4][d]; hi.y = tile[c * 8 + 5][d];
        hi.z = tile[c * 8 + 6][d]; hi.w = tile[c * 8 + 7][d];
        const size_t ob = ((size_t)bh * 96 + d) * 1024 + n0 + c * 8;
        *(ushort4*)&vT[ob]     = lo;
        *(ushort4*)&vT[ob + 4] = hi;
    }
}

// ---------------------------------------------------------------------------
// bf16 MFMA GEMM, NT form: C[M,N] = A[M,K] @ Bt[N,K]^T. (round-6, unchanged)
// MODE 0: bf16 out. MODE 1: fp32 out + bias, split-A (A + Alo).
// ---------------------------------------------------------------------------
template <int MODE>
__global__ __launch_bounds__(256) void mfma_gemm(
    const unsigned short* __restrict__ A,
    const unsigned short* __restrict__ Alo,
    const unsigned short* __restrict__ Bt,
    const float* __restrict__ bias,
    unsigned short* __restrict__ Cb, float* __restrict__ Cf,
    int N, int K)
{
    __shared__ unsigned short As[128 * 32];
    __shared__ unsigned short Bs[128 * 32];
    __shared__ unsigned short Als[MODE == 1 ? 128 * 32 : 8];

    const int tid  = threadIdx.x;
    const int lane = tid & 63, wv = tid >> 6;
    const int bm = blockIdx.y * 128, bn = blockIdx.x * 128;
    const int mcol = lane & 15, quad = lane >> 4;
    const int wr = (wv & 1) * 64, wc = (wv >> 1) * 64;
    const int srow = lane >> 2;
    const int skch = (lane & 3) * 8;

    f32x4 acc[4][4];
#pragma unroll
    for (int i = 0; i < 4; ++i)
#pragma unroll
        for (int j = 0; j < 4; ++j) acc[i][j] = (f32x4){0.f, 0.f, 0.f, 0.f};

    for (int k0 = 0; k0 < K; k0 += 32) {
#pragma unroll
        for (int c = 0; c < 2; ++c) {
            const int s = wv * 2 + c;
            const int row = s * 16 + srow;
            gll16(&A [(size_t)(bm + row) * K + k0 + skch], &As[s * 512]);
            gll16(&Bt[(size_t)(bn + row) * K + k0 + skch], &Bs[s * 512]);
            if (MODE == 1)
                gll16(&Alo[(size_t)(bm + row) * K + k0 + skch], &Als[s * 512]);
        }
        __syncthreads();

        bf16x8 af[4], bfr[4], al[4];
#pragma unroll
        for (int i = 0; i < 4; ++i) {
            af[i]  = *(const bf16x8*)&As[(wr + i * 16 + mcol) * 32 + quad * 8];
            bfr[i] = *(const bf16x8*)&Bs[(wc + i * 16 + mcol) * 32 + quad * 8];
            if (MODE == 1)
                al[i] = *(const bf16x8*)&Als[(wr + i * 16 + mcol) * 32 + quad * 8];
        }
#pragma unroll
        for (int i = 0; i < 4; ++i)
#pragma unroll
            for (int j = 0; j < 4; ++j) {
                acc[i][j] = __builtin_amdgcn_mfma_f32_16x16x32_bf16(af[i], bfr[j], acc[i][j], 0, 0, 0);
                if (MODE == 1)
                    acc[i][j] = __builtin_amdgcn_mfma_f32_16x16x32_bf16(al[i], bfr[j], acc[i][j], 0, 0, 0);
            }
        __syncthreads();
    }

#pragma unroll
    for (int j = 0; j < 4; ++j) {
        const int col = bn + wc + j * 16 + mcol;
        float bs = 0.f;
        if (MODE == 1) bs = bias[col];
#pragma unroll
        for (int i = 0; i < 4; ++i)
#pragma unroll
            for (int rg = 0; rg < 4; ++rg) {
                const int rrow = bm + wr + i * 16 + quad * 4 + rg;
                if (MODE == 0) Cb[(size_t)rrow * N + col] = f2bf(acc[i][j][rg]);
                else           Cf[(size_t)rrow * N + col] = acc[i][j][rg] + bs;
            }
    }
}

// ---------------------------------------------------------------------------
// Attention v6: 512-thread blocks (8 waves x 128 cols). Register logits d[8]
// (32 VGPR vs 64) -> ~24 waves/CU (was 16). Second-softmax max pass removed
// (inputs are probs in [0,1]; shift 0 is safe, masked -> exact 0), probs+mask+
// exp+bf16-store fused into one pass; 3 barriers (was 4). exp2-domain:
// log2e folded into Wqt scale (softmax 1) and into 1/S (softmax 2).
// C-layout: row=quad*4+rg, col=(wv*8+nt)*16+mcol; cls cols {0..19} live
// entirely in wave 0 (nt=0 all, nt=1 mcol<4).
// ---------------------------------------------------------------------------
__global__ __launch_bounds__(512, 6) void attn_kernel(
    const unsigned short* __restrict__ qb, const unsigned short* __restrict__ kv16,
    const unsigned short* __restrict__ vT,
    unsigned short* __restrict__ xh, unsigned short* __restrict__ xl)
{
    const int bid  = blockIdx.x;       // b*8*64 + h*64 + tile
    const int tile = bid & 63;
    const int h    = (bid >> 6) & 7;
    const int b    = bid >> 9;
    const int lq0  = tile * TQ;
    const int tid  = threadIdx.x;
    const int lane = tid & 63;
    const int wv   = tid >> 6;          // 0..7
    const int mcol = lane & 15;
    const int quad = lane >> 4;
    const int row0 = quad * 4;          // first of this lane's 4 C-rows

    __shared__ __align__(16) unsigned short sPb[16 * 1032];   // 33 KB
    __shared__ float sM1[8][16], sS1[8][16], sS2[8][16];
    __shared__ float sCm[16], sCs[16];

    // ---- QK^T via MFMA: wave wv covers cols [wv*128, wv*128+128) ----
    // logits arrive pre-scaled by SCALE*log2e (folded into Wqt).
    f32x4 d[8];
    {
        const unsigned short* qbb = qb + (size_t)(b * NT) * 768;
        const int qoff = (lq0 + mcol) * 768 + h * 96 + quad * 8;
        const bf16x8 qa0 = *(const bf16x8*)&qbb[qoff];
        const bf16x8 qa1 = *(const bf16x8*)&qbb[qoff + 32];
        const bf16x8 qa2 = *(const bf16x8*)&qbb[qoff + 64];
        const unsigned short* kvb = kv16 + (size_t)(b * NK) * 1536 + h * 96;
#pragma unroll
        for (int nt = 0; nt < 8; ++nt) {
            const int koff = (wv * 128 + nt * 16 + mcol) * 1536 + quad * 8;
            f32x4 acc = {0.f, 0.f, 0.f, 0.f};
            acc = __builtin_amdgcn_mfma_f32_16x16x32_bf16(qa0, *(const bf16x8*)&kvb[koff],      acc, 0, 0, 0);
            acc = __builtin_amdgcn_mfma_f32_16x16x32_bf16(qa1, *(const bf16x8*)&kvb[koff + 32], acc, 0, 0, 0);
            acc = __builtin_amdgcn_mfma_f32_16x16x32_bf16(qa2, *(const bf16x8*)&kvb[koff + 64], acc, 0, 0, 0);
            d[nt] = acc;
        }
    }

    // ---- threefry mask bits for this lane's 32 (row,col) elements ----
    // bit i = nt*4+rg. Rolled nt loop keeps code small (I-cache).
    uint32_t m0 = 0u;
    {
        const uint32_t rowg =
            ((uint32_t)(b * 8 + h) * (uint32_t)L_ + (uint32_t)(lq0 + row0 + CLS_)) * 1024u;
        for (int nt = 0; nt < 8; ++nt) {
            const uint32_t col = (uint32_t)(((wv * 8 + nt) << 4) + mcol);
            uint32_t acc = 0u;
#pragma unroll
            for (int rg = 0; rg < 4; ++rg) {
                uint32_t bits = tf_bits(rowg + 1024u * (uint32_t)rg + col);
                acc |= (bits < MASK_THR ? 1u : 0u) << rg;
            }
            m0 |= acc << (nt * 4);
        }
    }

    // ---- patch max (cols >= 20) ----
    float pmax[4] = {-INFINITY, -INFINITY, -INFINITY, -INFINITY};
#pragma unroll
    for (int nt = 0; nt < 8; ++nt) {
        if (wv == 0 && nt == 0) continue;               // cols 0..15: all cls
        bool clslane = (wv == 0 && nt == 1 && mcol < 4); // cols 16..19
#pragma unroll
        for (int rg = 0; rg < 4; ++rg)
            if (!clslane) pmax[rg] = fmaxf(pmax[rg], d[nt][rg]);
    }
#pragma unroll
    for (int rg = 0; rg < 4; ++rg)
#pragma unroll
        for (int m = 1; m <= 8; m <<= 1) pmax[rg] = fmaxf(pmax[rg], __shfl_xor(pmax[rg], m));
    if (mcol == 0)
#pragma unroll
        for (int rg = 0; rg < 4; ++rg) sM1[wv][row0 + rg] = pmax[rg];

    // ---- cls max (wave 0 only; cols 0..19) ----
    if (wv == 0) {
        float cmax[4];
#pragma unroll
        for (int rg = 0; rg < 4; ++rg) {
            float c = d[0][rg];
            if (mcol < 4) c = fmaxf(c, d[1][rg]);
            cmax[rg] = c;
        }
#pragma unroll
        for (int rg = 0; rg < 4; ++rg)
#pragma unroll
            for (int m = 1; m <= 8; m <<= 1) cmax[rg] = fmaxf(cmax[rg], __shfl_xor(cmax[rg], m));
        if (mcol == 0)
#pragma unroll
            for (int rg = 0; rg < 4; ++rg) sCm[row0 + rg] = cmax[rg];
    }
    __syncthreads();

    float pm[4], cm[4];
#pragma unroll
    for (int rg = 0; rg < 4; ++rg) {
        const int rr = row0 + rg;
        float a = fmaxf(fmaxf(sM1[0][rr], sM1[1][rr]), fmaxf(sM1[2][rr], sM1[3][rr]));
        float c = fmaxf(fmaxf(sM1[4][rr], sM1[5][rr]), fmaxf(sM1[6][rr], sM1[7][rr]));
        pm[rg] = fmaxf(a, c);
        cm[rg] = sCm[rr];
    }

    // ---- exp2 pass (in regs) + partial sums ----
    float ps[4] = {0.f, 0.f, 0.f, 0.f}, cs[4] = {0.f, 0.f, 0.f, 0.f};
#pragma unroll
    for (int nt = 0; nt < 8; ++nt) {
        const bool c_all = (wv == 0 && nt == 0);
        const bool c_few = (wv == 0 && nt == 1);
#pragma unroll
        for (int rg = 0; rg < 4; ++rg) {
            const bool iscls = c_all || (c_few && mcol < 4);
            float e = fexp2(d[nt][rg] - (iscls ? cm[rg] : pm[rg]));
            d[nt][rg] = e;
            if (iscls) cs[rg] += e; else ps[rg] += e;
        }
    }
#pragma unroll
    for (int rg = 0; rg < 4; ++rg)
#pragma unroll
        for (int m = 1; m <= 8; m <<= 1) ps[rg] += __shfl_xor(ps[rg], m);
    if (mcol == 0)
#pragma unroll
        for (int rg = 0; rg < 4; ++rg) sS1[wv][row0 + rg] = ps[rg];
    if (wv == 0) {
#pragma unroll
        for (int rg = 0; rg < 4; ++rg)
#pragma unroll
            for (int m = 1; m <= 8; m <<= 1) cs[rg] += __shfl_xor(cs[rg], m);
        if (mcol == 0)
#pragma unroll
            for (int rg = 0; rg < 4; ++rg) sCs[row0 + rg] = cs[rg];
    }
    __syncthreads();

    // 1/S with log2e folded in: e2 = exp2(e1 * (log2e/S)) = exp(p)
    float ipl[4], icl[4];
#pragma unroll
    for (int rg = 0; rg < 4; ++rg) {
        const int rr = row0 + rg;
        float s = sS1[0][rr] + sS1[1][rr] + sS1[2][rr] + sS1[3][rr]
                + sS1[4][rr] + sS1[5][rr] + sS1[6][rr] + sS1[7][rr];
        ipl[rg] = LOG2E_ / s;
        icl[rg] = LOG2E_ / sCs[rr];
    }

    // ---- fused: probs -> mask -> exp (shift 0) -> bf16 store + s2 partials ----
    float s2[4] = {0.f, 0.f, 0.f, 0.f};
#pragma unroll
    for (int nt = 0; nt < 8; ++nt) {
        const bool c_all = (wv == 0 && nt == 0);
        const bool c_few = (wv == 0 && nt == 1);
        const int col = (wv * 8 + nt) * 16 + mcol;
#pragma unroll
        for (int rg = 0; rg < 4; ++rg) {
            const bool iscls = c_all || (c_few && mcol < 4);
            float e2 = fexp2(d[nt][rg] * (iscls ? icl[rg] : ipl[rg]));
            const uint32_t bit = (m0 >> (nt * 4 + rg)) & 1u;
            e2 = bit ? 0.f : e2;              // == exp(p - 1e12) underflow
            s2[rg] += e2;
            sPb[(row0 + rg) * 1032 + col] = f2bf(e2);
        }
    }
#pragma unroll
    for (int rg = 0; rg < 4; ++rg)
#pragma unroll
        for (int m = 1; m <= 8; m <<= 1) s2[rg] += __shfl_xor(s2[rg], m);
    if (mcol == 0)
#pragma unroll
        for (int rg = 0; rg < 4; ++rg) sS2[wv][row0 + rg] = s2[rg];
    __syncthreads();

    // ---- PV via MFMA: waves 0..5 each own one 16-wide d-tile ----
    if (wv < 6) {
        const unsigned short* vb = vT + ((size_t)(b * 8 + h)) * 96 * 1024
                                 + (size_t)(wv * 16 + mcol) * 1024;
        f32x4 a0 = {0.f, 0.f, 0.f, 0.f};
#pragma unroll 4
        for (int k0 = 0; k0 < 1024; k0 += 32) {
            const bf16x8 pa = *(const bf16x8*)&sPb[mcol * 1032 + k0 + quad * 8];
            a0 = __builtin_amdgcn_mfma_f32_16x16x32_bf16(pa, *(const bf16x8*)&vb[k0 + quad * 8], a0, 0, 0, 0);
        }

        float inv[4];
#pragma unroll
        for (int rg = 0; rg < 4; ++rg) {
            const int rr = row0 + rg;
            float s = sS2[0][rr] + sS2[1][rr] + sS2[2][rr] + sS2[3][rr]
                    + sS2[4][rr] + sS2[5][rr] + sS2[6][rr] + sS2[7][rr];
            inv[rg] = 1.f / s;
        }
#pragma unroll
        for (int rg = 0; rg < 4; ++rg) {
            const size_t ob = ((size_t)(b * NT) + lq0 + row0 + rg) * 768 + h * 96;
            float val = a0[rg] * inv[rg];
            unsigned short hb = f2bf(val);
            xh[ob + wv * 16 + mcol] = hb;
            xl[ob + wv * 16 + mcol] = f2bf(val - __uint_as_float((uint32_t)hb << 16));
        }
    }
}

// ---------------------------------------------------------------------------
extern "C" void kernel_launch(void* const* d_in, const int* in_sizes, int n_in,
                              void* d_out, int out_size, void* d_ws, size_t ws_size,
                              hipStream_t stream)
{
    const float* in_q   = (const float*)d_in[0];
    const float* in_k   = (const float*)d_in[1];
    const float* Wq     = (const float*)d_in[2];
    const float* Wkv    = (const float*)d_in[3];
    // d_in[4] = Wcls — unused (cls query rows are dropped by the reference)
    const float* Wproj  = (const float*)d_in[5];
    const float* bproj  = (const float*)d_in[6];
    float* out = (float*)d_out;

    // workspace layout (bf16 units)
    unsigned short* ws16 = (unsigned short*)d_ws;
    unsigned short* Aq   = ws16;                  // 6291456
    unsigned short* Ak   = Aq   + 6291456;        // 6291456
    unsigned short* qb   = Ak   + 6291456;        // 6291456
    unsigned short* kv16 = qb   + 6291456;        // 12582912
    unsigned short* vT   = kv16 + 12582912;       // 6291456
    unsigned short* Wqt  = vT   + 6291456;        // 589824
    unsigned short* Wkvt = Wqt  + 589824;         // 1179648
    unsigned short* Wpt  = Wkvt + 1179648;        // 589824
    unsigned short* xh   = Aq;                    // reuse (dead after gemm_q)
    unsigned short* xl   = Ak;                    // reuse (dead after gemm_kv)

    dim3 blk(256);

    conv_bf16<<<6144, blk, 0, stream>>>(in_q, Aq, 1572864);
    conv_bf16<<<6144, blk, 0, stream>>>(in_k, Ak, 1572864);
    // SCALE * log2e folded into Wq so QK logits are in exp2 domain
    trw_bf16<<<dim3(24, 24), blk, 0, stream>>>(Wq,    Wqt,  768,  SCALE_ * LOG2E_);
    trw_bf16<<<dim3(48, 24), blk, 0, stream>>>(Wkv,   Wkvt, 1536, 1.f);
    trw_bf16<<<dim3(24, 24), blk, 0, stream>>>(Wproj, Wpt,  768,  1.f);

    mfma_gemm<0><<<dim3(6, 64), blk, 0, stream>>>(
        Aq, nullptr, Wqt, nullptr, qb, nullptr, 768, 768);

    mfma_gemm<0><<<dim3(12, 64), blk, 0, stream>>>(
        Ak, nullptr, Wkvt, nullptr, kv16, nullptr, 1536, 768);

    trv<<<1024, blk, 0, stream>>>(kv16, vT);

    attn_kernel<<<4096, dim3(512), 0, stream>>>(qb, kv16, vT, xh, xl);

    mfma_gemm<1><<<dim3(6, 64), blk, 0, stream>>>(
        xh, xl, Wpt, bproj, nullptr, out, 768, 768);
}

// Round 3
// 422.148 us; speedup vs baseline: 1.0840x; 1.0840x over previous
//
#include <hip/hip_runtime.h>
#include <cstdint>
#include <cstddef>

// Problem constants
#define B_ 8
#define NT 1024
#define NK 1024
#define D_ 768
#define H_ 8
#define HD_ 96
#define CLS_ 20
#define L_ 1044
#define SCALE_ 0.10206207261596577f
#define LOG2E_ 1.4426950408889634f
#define TQ 16
// integer mask threshold: bits < THR  <=>  uniform(bits) < 0.3f (exact)
#define MASK_THR 1288490496u

typedef __attribute__((ext_vector_type(8))) short bf16x8;
typedef __attribute__((ext_vector_type(4))) float f32x4;

__device__ __forceinline__ unsigned short f2bf(float f) {
    uint32_t u = __float_as_uint(f);
    u += 0x7FFFu + ((u >> 16) & 1u);   // RNE (no NaN inputs here)
    return (unsigned short)(u >> 16);
}

__device__ __forceinline__ float fexp2(float x) {
#if __has_builtin(__builtin_amdgcn_exp2f)
    return __builtin_amdgcn_exp2f(x);
#else
    return __expf(x * 0.6931471805599453f);
#endif
}

// async global->LDS, 16B per lane; LDS dest = wave-uniform base + lane*16
__device__ __forceinline__ void gll16(const void* g, void* l) {
    __builtin_amdgcn_global_load_lds(
        (const __attribute__((address_space(1))) unsigned int*)g,
        (__attribute__((address_space(3))) unsigned int*)l,
        16, 0, 0);
}

// ---------------------------------------------------------------------------
// JAX threefry2x32, partitionable scheme (verified): counter = (0, g),
// output bits = x0 ^ x1. key = (0, 42).
// ---------------------------------------------------------------------------
__device__ __forceinline__ uint32_t tf_bits(uint32_t g) {
    const uint32_t k0 = 0u, k1 = 42u;
    const uint32_t ks2 = k0 ^ k1 ^ 0x1BD11BDAu;
    uint32_t x0 = 0u, x1 = g;

    x0 += k0; x1 += k1;
#define TF_ROUND(r) { x0 += x1; x1 = __builtin_rotateleft32(x1, (r)); x1 ^= x0; }
    TF_ROUND(13) TF_ROUND(15) TF_ROUND(26) TF_ROUND(6)
    x0 += k1;  x1 += ks2 + 1u;
    TF_ROUND(17) TF_ROUND(29) TF_ROUND(16) TF_ROUND(24)
    x0 += ks2; x1 += k0 + 2u;
    TF_ROUND(13) TF_ROUND(15) TF_ROUND(26) TF_ROUND(6)
    x0 += k0;  x1 += k1 + 3u;
    TF_ROUND(17) TF_ROUND(29) TF_ROUND(16) TF_ROUND(24)
    x0 += k1;  x1 += ks2 + 4u;
    TF_ROUND(13) TF_ROUND(15) TF_ROUND(26) TF_ROUND(6)
    x0 += ks2; x1 += k0 + 5u;
#undef TF_ROUND
    return x0 ^ x1;
}

// ---------------------------------------------------------------------------
// fp32 -> bf16 flat convert, two arrays in one launch (saves a launch gap)
// ---------------------------------------------------------------------------
__global__ __launch_bounds__(256) void conv2_bf16(
    const float* __restrict__ srcA, unsigned short* __restrict__ dstA,
    const float* __restrict__ srcB, unsigned short* __restrict__ dstB, int n4)
{
    int i = blockIdx.x * 256 + threadIdx.x;
    const float* s = srcA;
    unsigned short* d = dstA;
    if (i >= n4) { i -= n4; s = srcB; d = dstB; }
    float4 v = ((const float4*)s)[i];
    ushort4 o;
    o.x = f2bf(v.x); o.y = f2bf(v.y); o.z = f2bf(v.z); o.w = f2bf(v.w);
    ((ushort4*)d)[i] = o;
}

// ---------------------------------------------------------------------------
// weight transpose: W[768][Nn] fp32 -> Wt[Nn][768] bf16 (* scale), 32x32
// tiles. All three weights in one launch (grid.z selects).
// ---------------------------------------------------------------------------
__global__ __launch_bounds__(256) void trw_all(
    const float* __restrict__ Wq, const float* __restrict__ Wkv,
    const float* __restrict__ Wproj,
    unsigned short* __restrict__ Wqt, unsigned short* __restrict__ Wkvt,
    unsigned short* __restrict__ Wpt, float scaleq)
{
    const int z = blockIdx.z;
    const float* W; unsigned short* Wt; int Nn; float scale;
    if (z == 0)      { W = Wq;    Wt = Wqt;  Nn = 768;  scale = scaleq; }
    else if (z == 1) { W = Wkv;   Wt = Wkvt; Nn = 1536; scale = 1.f; }
    else             { W = Wproj; Wt = Wpt;  Nn = 768;  scale = 1.f; }
    if (blockIdx.x * 32 >= Nn) return;   // whole block exits; no barrier issue

    __shared__ unsigned short tile[32][36];
    const int n0 = blockIdx.x * 32, k0 = blockIdx.y * 32;
    const int t = threadIdx.x, r = t >> 3, c4 = (t & 7) * 4;

    float4 v = *(const float4*)&W[(size_t)(k0 + r) * Nn + n0 + c4];
    tile[r][c4 + 0] = f2bf(v.x * scale);
    tile[r][c4 + 1] = f2bf(v.y * scale);
    tile[r][c4 + 2] = f2bf(v.z * scale);
    tile[r][c4 + 3] = f2bf(v.w * scale);
    __syncthreads();

    ushort4 o;
    o.x = tile[c4 + 0][r];
    o.y = tile[c4 + 1][r];
    o.z = tile[c4 + 2][r];
    o.w = tile[c4 + 3][r];
    *(ushort4*)&Wt[(size_t)(n0 + r) * 768 + k0 + c4] = o;
}

// ---------------------------------------------------------------------------
// V transpose: kv16[8192][1536] bf16 (V half at col 768+h*96) ->
//              vT[(b*8+h)*96 + d][1024] bf16
// ---------------------------------------------------------------------------
__global__ __launch_bounds__(256) void trv(
    const unsigned short* __restrict__ kv16, unsigned short* __restrict__ vT)
{
    const int bid = blockIdx.x;       // (b*8+h)*16 + nt
    const int nt = bid & 15, bh = bid >> 4;
    const int b = bh >> 3, h = bh & 7;
    const int n0 = nt * 64;
    const int t = threadIdx.x;

    __shared__ unsigned short tile[64][104];

    for (int i = t; i < 768; i += 256) {
        int r = i / 12, c = i % 12;
        *(uint4*)&tile[r][c * 8] =
            *(const uint4*)&kv16[(size_t)(b * 1024 + n0 + r) * 1536 + 768 + h * 96 + c * 8];
    }
    __syncthreads();

    for (int i = t; i < 768; i += 256) {
        int d = i >> 3, c = i & 7;
        ushort4 lo, hi;
        lo.x = tile[c * 8 + 0][d]; lo.y = tile[c * 8 + 1][d];
        lo.z = tile[c * 8 + 2][d]; lo.w = tile[c * 8 + 3][d];
        hi.x = tile[c * 8 + 4][d]; hi.y = tile[c * 8 + 5][d];
        hi.z = tile[c * 8 + 6][d]; hi.w = tile[c * 8 + 7][d];
        const size_t ob = ((size_t)bh * 96 + d) * 1024 + n0 + c * 8;
        *(ushort4*)&vT[ob]     = lo;
        *(ushort4*)&vT[ob + 4] = hi;
    }
}

// ---------------------------------------------------------------------------
// bf16 MFMA GEMM, NT form: C[M,N] = A[M,K] @ Bt[N,K]^T.
// MODE 0: bf16 out. MODE 1: fp32 out + bias, split-A (A + Alo).
// ---------------------------------------------------------------------------
template <int MODE>
__global__ __launch_bounds__(256) void mfma_gemm(
    const unsigned short* __restrict__ A,
    const unsigned short* __restrict__ Alo,
    const unsigned short* __restrict__ Bt,
    const float* __restrict__ bias,
    unsigned short* __restrict__ Cb, float* __restrict__ Cf,
    int N, int K)
{
    __shared__ unsigned short As[128 * 32];
    __shared__ unsigned short Bs[128 * 32];
    __shared__ unsigned short Als[MODE == 1 ? 128 * 32 : 8];

    const int tid  = threadIdx.x;
    const int lane = tid & 63, wv = tid >> 6;
    const int bm = blockIdx.y * 128, bn = blockIdx.x * 128;
    const int mcol = lane & 15, quad = lane >> 4;
    const int wr = (wv & 1) * 64, wc = (wv >> 1) * 64;
    const int srow = lane >> 2;
    const int skch = (lane & 3) * 8;

    f32x4 acc[4][4];
#pragma unroll
    for (int i = 0; i < 4; ++i)
#pragma unroll
        for (int j = 0; j < 4; ++j) acc[i][j] = (f32x4){0.f, 0.f, 0.f, 0.f};

    for (int k0 = 0; k0 < K; k0 += 32) {
#pragma unroll
        for (int c = 0; c < 2; ++c) {
            const int s = wv * 2 + c;
            const int row = s * 16 + srow;
            gll16(&A [(size_t)(bm + row) * K + k0 + skch], &As[s * 512]);
            gll16(&Bt[(size_t)(bn + row) * K + k0 + skch], &Bs[s * 512]);
            if (MODE == 1)
                gll16(&Alo[(size_t)(bm + row) * K + k0 + skch], &Als[s * 512]);
        }
        __syncthreads();

        bf16x8 af[4], bfr[4], al[4];
#pragma unroll
        for (int i = 0; i < 4; ++i) {
            af[i]  = *(const bf16x8*)&As[(wr + i * 16 + mcol) * 32 + quad * 8];
            bfr[i] = *(const bf16x8*)&Bs[(wc + i * 16 + mcol) * 32 + quad * 8];
            if (MODE == 1)
                al[i] = *(const bf16x8*)&Als[(wr + i * 16 + mcol) * 32 + quad * 8];
        }
#pragma unroll
        for (int i = 0; i < 4; ++i)
#pragma unroll
            for (int j = 0; j < 4; ++j) {
                acc[i][j] = __builtin_amdgcn_mfma_f32_16x16x32_bf16(af[i], bfr[j], acc[i][j], 0, 0, 0);
                if (MODE == 1)
                    acc[i][j] = __builtin_amdgcn_mfma_f32_16x16x32_bf16(al[i], bfr[j], acc[i][j], 0, 0, 0);
            }
        __syncthreads();
    }

#pragma unroll
    for (int j = 0; j < 4; ++j) {
        const int col = bn + wc + j * 16 + mcol;
        float bs = 0.f;
        if (MODE == 1) bs = bias[col];
#pragma unroll
        for (int i = 0; i < 4; ++i)
#pragma unroll
            for (int rg = 0; rg < 4; ++rg) {
                const int rrow = bm + wr + i * 16 + quad * 4 + rg;
                if (MODE == 0) Cb[(size_t)rrow * N + col] = f2bf(acc[i][j][rg]);
                else           Cf[(size_t)rrow * N + col] = acc[i][j][rg] + bs;
            }
    }
}

// ---------------------------------------------------------------------------
// Attention v7: 256-thread / 4-wave phase structure (proven best: dual-chain
// PV ILP, narrow barriers) + v6's VALU reductions (verified bit-compatible):
// no second-max pass, fused probs+mask+exp+store, 3 barriers, exp2-domain
// (SCALE*log2e folded into Wqt; log2e/S folded into reciprocal), setprio
// around PV MFMA chain (T5). LDS ~34 KB, d[16] accum -> ~4 waves/SIMD.
// C-layout: row=quad*4+rg, col=(wv*16+nt)*16+mcol; cls cols {0..19} live
// entirely in wave 0 (nt=0 all, nt=1 mcol<4).
// ---------------------------------------------------------------------------
__global__ __launch_bounds__(256, 4) void attn_kernel(
    const unsigned short* __restrict__ qb, const unsigned short* __restrict__ kv16,
    const unsigned short* __restrict__ vT,
    unsigned short* __restrict__ xh, unsigned short* __restrict__ xl)
{
    const int bid  = blockIdx.x;       // b*8*64 + h*64 + tile
    const int tile = bid & 63;
    const int h    = (bid >> 6) & 7;
    const int b    = bid >> 9;
    const int lq0  = tile * TQ;
    const int tid  = threadIdx.x;
    const int lane = tid & 63;
    const int wv   = tid >> 6;          // 0..3
    const int mcol = lane & 15;
    const int quad = lane >> 4;
    const int row0 = quad * 4;          // first of this lane's 4 C-rows

    __shared__ __align__(16) unsigned short sPb[16 * 1032];   // 33 KB
    __shared__ float sM1[4][16], sS1[4][16], sS2[4][16];
    __shared__ float sCm[16], sCs[16];

    // ---- QK^T via MFMA: wave wv covers cols [wv*256, wv*256+256) ----
    // logits arrive pre-scaled by SCALE*log2e (folded into Wqt).
    f32x4 d[16];
    {
        const size_t qrow = ((size_t)(b * NT) + lq0 + mcol) * 768 + h * 96 + quad * 8;
        const bf16x8 qa0 = *(const bf16x8*)&qb[qrow];
        const bf16x8 qa1 = *(const bf16x8*)&qb[qrow + 32];
        const bf16x8 qa2 = *(const bf16x8*)&qb[qrow + 64];
#pragma unroll
        for (int nt = 0; nt < 16; ++nt) {
            const int n0 = (wv * 16 + nt) * 16;
            const size_t krow = ((size_t)(b * NK) + n0 + mcol) * 1536 + h * 96 + quad * 8;
            f32x4 acc = {0.f, 0.f, 0.f, 0.f};
            acc = __builtin_amdgcn_mfma_f32_16x16x32_bf16(qa0, *(const bf16x8*)&kv16[krow],      acc, 0, 0, 0);
            acc = __builtin_amdgcn_mfma_f32_16x16x32_bf16(qa1, *(const bf16x8*)&kv16[krow + 32], acc, 0, 0, 0);
            acc = __builtin_amdgcn_mfma_f32_16x16x32_bf16(qa2, *(const bf16x8*)&kv16[krow + 64], acc, 0, 0, 0);
            d[nt] = acc;
        }
    }

    // ---- threefry mask bits for this lane's 64 (row,col) elements ----
    uint32_t m0 = 0u, m1 = 0u;
    {
        const uint32_t rowg =
            ((uint32_t)(b * 8 + h) * (uint32_t)L_ + (uint32_t)(lq0 + row0 + CLS_)) * 1024u;
        for (int nt = 0; nt < 16; ++nt) {
            const uint32_t col = (uint32_t)(((wv * 16 + nt) << 4) + mcol);
            uint32_t acc = 0u;
#pragma unroll
            for (int rg = 0; rg < 4; ++rg) {
                uint32_t bits = tf_bits(rowg + 1024u * (uint32_t)rg + col);
                acc |= (bits < MASK_THR ? 1u : 0u) << rg;
            }
            if (nt < 8) m0 |= acc << (nt * 4);
            else        m1 |= acc << ((nt - 8) * 4);
        }
    }

    // ---- patch max (cols >= 20) ----
    float pmax[4] = {-INFINITY, -INFINITY, -INFINITY, -INFINITY};
#pragma unroll
    for (int nt = 0; nt < 16; ++nt) {
        if (wv == 0 && nt == 0) continue;               // cols 0..15: all cls
        bool clslane = (wv == 0 && nt == 1 && mcol < 4); // cols 16..19
#pragma unroll
        for (int rg = 0; rg < 4; ++rg)
            if (!clslane) pmax[rg] = fmaxf(pmax[rg], d[nt][rg]);
    }
#pragma unroll
    for (int rg = 0; rg < 4; ++rg)
#pragma unroll
        for (int m = 1; m <= 8; m <<= 1) pmax[rg] = fmaxf(pmax[rg], __shfl_xor(pmax[rg], m));
    if (mcol == 0)
#pragma unroll
        for (int rg = 0; rg < 4; ++rg) sM1[wv][row0 + rg] = pmax[rg];

    // ---- cls max (wave 0 only; cols 0..19) ----
    if (wv == 0) {
        float cmax[4];
#pragma unroll
        for (int rg = 0; rg < 4; ++rg) {
            float c = d[0][rg];
            if (mcol < 4) c = fmaxf(c, d[1][rg]);
            cmax[rg] = c;
        }
#pragma unroll
        for (int rg = 0; rg < 4; ++rg)
#pragma unroll
            for (int m = 1; m <= 8; m <<= 1) cmax[rg] = fmaxf(cmax[rg], __shfl_xor(cmax[rg], m));
        if (mcol == 0)
#pragma unroll
            for (int rg = 0; rg < 4; ++rg) sCm[row0 + rg] = cmax[rg];
    }
    __syncthreads();

    float pm[4], cm[4];
#pragma unroll
    for (int rg = 0; rg < 4; ++rg) {
        const int rr = row0 + rg;
        pm[rg] = fmaxf(fmaxf(sM1[0][rr], sM1[1][rr]), fmaxf(sM1[2][rr], sM1[3][rr]));
        cm[rg] = sCm[rr];
    }

    // ---- exp2 pass (in regs) + partial sums ----
    float ps[4] = {0.f, 0.f, 0.f, 0.f}, cs[4] = {0.f, 0.f, 0.f, 0.f};
#pragma unroll
    for (int nt = 0; nt < 16; ++nt) {
        const bool c_all = (wv == 0 && nt == 0);
        const bool c_few = (wv == 0 && nt == 1);
#pragma unroll
        for (int rg = 0; rg < 4; ++rg) {
            const bool iscls = c_all || (c_few && mcol < 4);
            float e = fexp2(d[nt][rg] - (iscls ? cm[rg] : pm[rg]));
            d[nt][rg] = e;
            if (iscls) cs[rg] += e; else ps[rg] += e;
        }
    }
#pragma unroll
    for (int rg = 0; rg < 4; ++rg)
#pragma unroll
        for (int m = 1; m <= 8; m <<= 1) ps[rg] += __shfl_xor(ps[rg], m);
    if (mcol == 0)
#pragma unroll
        for (int rg = 0; rg < 4; ++rg) sS1[wv][row0 + rg] = ps[rg];
    if (wv == 0) {
#pragma unroll
        for (int rg = 0; rg < 4; ++rg)
#pragma unroll
            for (int m = 1; m <= 8; m <<= 1) cs[rg] += __shfl_xor(cs[rg], m);
        if (mcol == 0)
#pragma unroll
            for (int rg = 0; rg < 4; ++rg) sCs[row0 + rg] = cs[rg];
    }
    __syncthreads();

    // 1/S with log2e folded in: e2 = exp2(e1 * (log2e/S)) = exp(p)
    float ipl[4], icl[4];
#pragma unroll
    for (int rg = 0; rg < 4; ++rg) {
        const int rr = row0 + rg;
        float s = sS1[0][rr] + sS1[1][rr] + sS1[2][rr] + sS1[3][rr];
        ipl[rg] = LOG2E_ / s;
        icl[rg] = LOG2E_ / sCs[rr];
    }

    // ---- fused: probs -> mask -> exp (shift 0) -> bf16 store + s2 partials ----
    float s2[4] = {0.f, 0.f, 0.f, 0.f};
#pragma unroll
    for (int nt = 0; nt < 16; ++nt) {
        const bool c_all = (wv == 0 && nt == 0);
        const bool c_few = (wv == 0 && nt == 1);
        const int col = (wv * 16 + nt) * 16 + mcol;
#pragma unroll
        for (int rg = 0; rg < 4; ++rg) {
            const bool iscls = c_all || (c_few && mcol < 4);
            float e2 = fexp2(d[nt][rg] * (iscls ? icl[rg] : ipl[rg]));
            const int i = nt * 4 + rg;
            const uint32_t bit = (i < 32) ? (m0 >> i) : (m1 >> (i - 32));
            e2 = (bit & 1u) ? 0.f : e2;       // == exp(p - 1e12) underflow
            s2[rg] += e2;
            sPb[(row0 + rg) * 1032 + col] = f2bf(e2);
        }
    }
#pragma unroll
    for (int rg = 0; rg < 4; ++rg)
#pragma unroll
        for (int m = 1; m <= 8; m <<= 1) s2[rg] += __shfl_xor(s2[rg], m);
    if (mcol == 0)
#pragma unroll
        for (int rg = 0; rg < 4; ++rg) sS2[wv][row0 + rg] = s2[rg];
    __syncthreads();

    // ---- PV via MFMA: wave wv owns d-tiles {wv, wv+4 (if <6)} ----
    {
        const int t0 = wv, t1 = wv + 4;
        const size_t vbase = ((size_t)(b * 8 + h)) * 96 * 1024;
        f32x4 a0 = {0.f, 0.f, 0.f, 0.f};
        f32x4 a1 = {0.f, 0.f, 0.f, 0.f};
        __builtin_amdgcn_s_setprio(1);
#pragma unroll 4
        for (int k0 = 0; k0 < 1024; k0 += 32) {
            const bf16x8 pa = *(const bf16x8*)&sPb[mcol * 1032 + k0 + quad * 8];
            const size_t v0 = vbase + (size_t)(t0 * 16 + mcol) * 1024 + k0 + quad * 8;
            a0 = __builtin_amdgcn_mfma_f32_16x16x32_bf16(pa, *(const bf16x8*)&vT[v0], a0, 0, 0, 0);
            if (t1 < 6) {
                const size_t v1 = vbase + (size_t)(t1 * 16 + mcol) * 1024 + k0 + quad * 8;
                a1 = __builtin_amdgcn_mfma_f32_16x16x32_bf16(pa, *(const bf16x8*)&vT[v1], a1, 0, 0, 0);
            }
        }
        __builtin_amdgcn_s_setprio(0);

        float inv[4];
#pragma unroll
        for (int rg = 0; rg < 4; ++rg) {
            const int rr = row0 + rg;
            inv[rg] = 1.f / (sS2[0][rr] + sS2[1][rr] + sS2[2][rr] + sS2[3][rr]);
        }
#pragma unroll
        for (int rg = 0; rg < 4; ++rg) {
            const size_t ob = ((size_t)(b * NT) + lq0 + row0 + rg) * 768 + h * 96;
            {
                float val = a0[rg] * inv[rg];
                unsigned short hb = f2bf(val);
                xh[ob + t0 * 16 + mcol] = hb;
                xl[ob + t0 * 16 + mcol] = f2bf(val - __uint_as_float((uint32_t)hb << 16));
            }
            if (t1 < 6) {
                float val = a1[rg] * inv[rg];
                unsigned short hb = f2bf(val);
                xh[ob + t1 * 16 + mcol] = hb;
                xl[ob + t1 * 16 + mcol] = f2bf(val - __uint_as_float((uint32_t)hb << 16));
            }
        }
    }
}

// ---------------------------------------------------------------------------
extern "C" void kernel_launch(void* const* d_in, const int* in_sizes, int n_in,
                              void* d_out, int out_size, void* d_ws, size_t ws_size,
                              hipStream_t stream)
{
    const float* in_q   = (const float*)d_in[0];
    const float* in_k   = (const float*)d_in[1];
    const float* Wq     = (const float*)d_in[2];
    const float* Wkv    = (const float*)d_in[3];
    // d_in[4] = Wcls — unused (cls query rows are dropped by the reference)
    const float* Wproj  = (const float*)d_in[5];
    const float* bproj  = (const float*)d_in[6];
    float* out = (float*)d_out;

    // workspace layout (bf16 units)
    unsigned short* ws16 = (unsigned short*)d_ws;
    unsigned short* Aq   = ws16;                  // 6291456
    unsigned short* Ak   = Aq   + 6291456;        // 6291456
    unsigned short* qb   = Ak   + 6291456;        // 6291456
    unsigned short* kv16 = qb   + 6291456;        // 12582912
    unsigned short* vT   = kv16 + 12582912;       // 6291456
    unsigned short* Wqt  = vT   + 6291456;        // 589824
    unsigned short* Wkvt = Wqt  + 589824;         // 1179648
    unsigned short* Wpt  = Wkvt + 1179648;        // 589824
    unsigned short* xh   = Aq;                    // reuse (dead after gemm_q)
    unsigned short* xl   = Ak;                    // reuse (dead after gemm_kv)

    dim3 blk(256);

    conv2_bf16<<<12288, blk, 0, stream>>>(in_q, Aq, in_k, Ak, 1572864);
    // SCALE * log2e folded into Wq so QK logits are in exp2 domain
    trw_all<<<dim3(48, 24, 3), blk, 0, stream>>>(
        Wq, Wkv, Wproj, Wqt, Wkvt, Wpt, SCALE_ * LOG2E_);

    mfma_gemm<0><<<dim3(6, 64), blk, 0, stream>>>(
        Aq, nullptr, Wqt, nullptr, qb, nullptr, 768, 768);

    mfma_gemm<0><<<dim3(12, 64), blk, 0, stream>>>(
        Ak, nullptr, Wkvt, nullptr, kv16, nullptr, 1536, 768);

    trv<<<1024, blk, 0, stream>>>(kv16, vT);

    attn_kernel<<<4096, blk, 0, stream>>>(qb, kv16, vT, xh, xl);

    mfma_gemm<1><<<dim3(6, 64), blk, 0, stream>>>(
        xh, xl, Wpt, bproj, nullptr, out, 768, 768);
}